// Round 12
// baseline (171.541 us; speedup 1.0000x reference)
//
#include <hip/hip_runtime.h>
#include <math.h>

#define TT 2
#define CH 128
#define HH 96
#define WW 96
#define HWS 9216            // H*W
#define QTOT 18432          // T*H*W
#define QC (QTOT*CH)
#define HD 32
#define KTOP 16
#define SCALE 0.17677669529663687f  // 32^-0.5

#define SEG 16              // queries per attn block (one row segment)
#define PR 8                // patch rows
#define PC 23               // patch cols

#define FPX 32              // pixels per fused dw+qkv block

// wbuf (bf16 shorts): wq_hi@0 wq_lo@16384 wk_hi@32768 wk_lo@49152 wv_hi@65536 pj_hi@81920
#define WB_TOT 98304

typedef __attribute__((ext_vector_type(8))) short short8;
typedef __attribute__((ext_vector_type(4))) float floatx4;

__device__ __forceinline__ unsigned short f2bf(float f) {
    union { float f; unsigned u; } x; x.f = f;
    unsigned r = x.u + 0x7fffu + ((x.u >> 16) & 1u);
    return (unsigned short)(r >> 16);
}
__device__ __forceinline__ float bf2f(unsigned short h) {
    return __uint_as_float(((unsigned)h) << 16);
}

__device__ __forceinline__ int refl(int x, int n) {
    x = x < 0 ? -x : x;
    return x >= n ? 2 * (n - 1) - x : x;
}

// ------ one-shot pointwise/proj weight conversion (4 blocks; runs BEFORE dwqkv) -----
__global__ __launch_bounds__(256) void wprep_kernel(
    const float* __restrict__ wq_pw, const float* __restrict__ wk_pw,
    const float* __restrict__ wv_pw, const float* __restrict__ proj_w,
    unsigned short* __restrict__ wbuf)
{
    int t = threadIdx.x;
    int y = blockIdx.x;               // 0=wq_pw(hi+lo) 1=wk_pw(hi+lo) 2=wv_pw 3=proj_w
    const float* src = y == 0 ? wq_pw : (y == 1 ? wk_pw : (y == 2 ? wv_pw : proj_w));
    unsigned short* hi = wbuf + (y == 0 ? 0 : (y == 1 ? 32768 : (y == 2 ? 65536 : 81920)));
#pragma unroll
    for (int r = 0; r < 16; r++) {
        int idx = r * 256 + t;        // float4 index, 4096 total = 128x128
        float4 w4 = *(const float4*)(src + idx * 4);
        unsigned short hx = f2bf(w4.x), hy = f2bf(w4.y), hz = f2bf(w4.z), hw = f2bf(w4.w);
        uint2 pk;
        pk.x = hx | ((unsigned)hy << 16); pk.y = hz | ((unsigned)hw << 16);
        *(uint2*)(hi + idx * 4) = pk;
        if (y < 2) {
            unsigned short lx = f2bf(w4.x - bf2f(hx)), ly = f2bf(w4.y - bf2f(hy));
            unsigned short lz = f2bf(w4.z - bf2f(hz)), lw = f2bf(w4.w - bf2f(hw));
            pk.x = lx | ((unsigned)ly << 16); pk.y = lz | ((unsigned)lw << 16);
            *(uint2*)(hi + 16384 + idx * 4) = pk;
        }
    }
}

// ------ FUSED depthwise 3x3 + bf16 split + qkv GEMMs (unchanged from r11) -----------
__global__ __launch_bounds__(512) void dwqkv_kernel(
    const float* __restrict__ x,
    const float* __restrict__ wqd, const float* __restrict__ wkd, const float* __restrict__ wvd,
    const unsigned short* __restrict__ wbuf,
    const float* __restrict__ bq, const float* __restrict__ bk, const float* __restrict__ bv,
    float* __restrict__ qkf,            // q -> qkf[0], k -> qkf[1] ([p][c] fp32)
    unsigned short* __restrict__ vh)    // [4][QTOT][32] bf16
{
    __shared__ float wS[3456];                    // 13.8 KB: wq|wk|wv dw taps (128x9 each)
    __shared__ unsigned short pl[5][FPX * 136];   // 43.5 KB: q_hi,q_lo,k_hi,k_lo,v
    int t = threadIdx.x;
    for (int r = t; r < 1152; r += 512) {
        wS[r] = wqd[r]; wS[1152 + r] = wkd[r]; wS[2304 + r] = wvd[r];
    }
    int p0 = blockIdx.x * FPX;
    int tt0 = p0 / HWS;
    int hw0 = p0 - tt0 * HWS;
    int i0 = hw0 / WW, j0 = hw0 - i0 * WW;        // block-uniform (32 | 96)
    int px = t & 31, cgp = t >> 5;                // cgp in [0,16)
    int c0 = cgp * 8;
    int j = j0 + px;

    int off[9]; float mk[9];
#pragma unroll
    for (int r = 0; r < 3; r++) {
        int ii = i0 + r - 1;
        float rm = (ii >= 0 && ii < HH) ? 1.f : 0.f;
        int iic = ii < 0 ? 0 : (ii >= HH ? HH - 1 : ii);
#pragma unroll
        for (int s = 0; s < 3; s++) {
            int jj = j + s - 1;
            float cm = (jj >= 0 && jj < WW) ? 1.f : 0.f;
            int jjc = jj < 0 ? 0 : (jj >= WW ? WW - 1 : jj);
            off[r * 3 + s] = iic * WW + jjc;
            mk[r * 3 + s] = rm * cm;
        }
    }
    __syncthreads();   // weights staged

    unsigned qh[4], ql2[4], kh[4], kl[4], vh4[4];
#pragma unroll
    for (int ic = 0; ic < 8; ic += 2) {
        float sv[3][2];
#pragma unroll
        for (int u = 0; u < 2; u++) {
            int c = c0 + ic + u;
            const float* xp = x + (size_t)(tt0 * CH + c) * HWS;
            const float* w0 = &wS[c * 9];
            const float* w1 = &wS[1152 + c * 9];
            const float* w2 = &wS[2304 + c * 9];
            float s0 = 0.f, s1 = 0.f, s2 = 0.f;
#pragma unroll
            for (int q9 = 0; q9 < 9; q9++) {
                float xv = xp[off[q9]] * mk[q9];   // mask=1 -> exact; mask=0 -> +0.0
                s0 += xv * w0[q9]; s1 += xv * w1[q9]; s2 += xv * w2[q9];
            }
            sv[0][u] = s0; sv[1][u] = s1; sv[2][u] = s2;
        }
        int w = ic >> 1;
        unsigned short h0 = f2bf(sv[0][0]), h1 = f2bf(sv[0][1]);
        qh[w] = h0 | ((unsigned)h1 << 16);
        ql2[w] = f2bf(sv[0][0] - bf2f(h0)) | ((unsigned)f2bf(sv[0][1] - bf2f(h1)) << 16);
        h0 = f2bf(sv[1][0]); h1 = f2bf(sv[1][1]);
        kh[w] = h0 | ((unsigned)h1 << 16);
        kl[w] = f2bf(sv[1][0] - bf2f(h0)) | ((unsigned)f2bf(sv[1][1] - bf2f(h1)) << 16);
        vh4[w] = f2bf(sv[2][0]) | ((unsigned)f2bf(sv[2][1]) << 16);
    }
    int lb = px * 136 + c0;
    uint4 pk;
    pk.x = qh[0];  pk.y = qh[1];  pk.z = qh[2];  pk.w = qh[3];  *(uint4*)&pl[0][lb] = pk;
    pk.x = ql2[0]; pk.y = ql2[1]; pk.z = ql2[2]; pk.w = ql2[3]; *(uint4*)&pl[1][lb] = pk;
    pk.x = kh[0];  pk.y = kh[1];  pk.z = kh[2];  pk.w = kh[3];  *(uint4*)&pl[2][lb] = pk;
    pk.x = kl[0];  pk.y = kl[1];  pk.z = kl[2];  pk.w = kl[3];  *(uint4*)&pl[3][lb] = pk;
    pk.x = vh4[0]; pk.y = vh4[1]; pk.z = vh4[2]; pk.w = vh4[3]; *(uint4*)&pl[4][lb] = pk;
    __syncthreads();

    // ---- phase 2: GEMMs. waves 0-3: q, waves 4-7: k (o0 = (wv&3)*32)
    int wv = t >> 6, lane = t & 63;
    int m = lane & 15, quad = lane >> 4;
    int o0 = (wv & 3) * 32;
    bool isQ = wv < 4;
    const unsigned short* Wh_g = wbuf + (isQ ? 0 : 32768);
    const unsigned short* Wl_g = Wh_g + 16384;
    const unsigned short* Ah = pl[isQ ? 0 : 2];
    const unsigned short* Al = pl[isQ ? 1 : 3];
    const float* bias = isQ ? bq : bk;
    float scale = isQ ? SCALE : 1.f;
    float* O = qkf + (isQ ? 0 : (size_t)QC);
    float bb[2];
#pragma unroll
    for (int ot = 0; ot < 2; ot++) bb[ot] = bias[o0 + ot * 16 + m];
    floatx4 acc[2][2];
#pragma unroll
    for (int i = 0; i < 2; i++)
#pragma unroll
        for (int jj2 = 0; jj2 < 2; jj2++) acc[i][jj2] = (floatx4){0.f, 0.f, 0.f, 0.f};
#pragma unroll
    for (int kc = 0; kc < 4; kc++) {
        short8 avh[2], avl[2], bh2[2], bl2[2];
#pragma unroll
        for (int pt = 0; pt < 2; pt++) {
            int lidx = (pt * 16 + m) * 136 + kc * 32 + quad * 8;
            avh[pt] = *(const short8*)&Ah[lidx];
            avl[pt] = *(const short8*)&Al[lidx];
        }
#pragma unroll
        for (int ot = 0; ot < 2; ot++) {
            size_t widx = (size_t)(o0 + ot * 16 + m) * CH + kc * 32 + quad * 8;
            bh2[ot] = *(const short8*)(Wh_g + widx);
            bl2[ot] = *(const short8*)(Wl_g + widx);
        }
#pragma unroll
        for (int pt = 0; pt < 2; pt++)
#pragma unroll
            for (int ot = 0; ot < 2; ot++) {
                acc[pt][ot] = __builtin_amdgcn_mfma_f32_16x16x32_bf16(avh[pt], bh2[ot], acc[pt][ot], 0, 0, 0);
                acc[pt][ot] = __builtin_amdgcn_mfma_f32_16x16x32_bf16(avh[pt], bl2[ot], acc[pt][ot], 0, 0, 0);
                acc[pt][ot] = __builtin_amdgcn_mfma_f32_16x16x32_bf16(avl[pt], bh2[ot], acc[pt][ot], 0, 0, 0);
            }
    }
#pragma unroll
    for (int pt = 0; pt < 2; pt++)
#pragma unroll
        for (int ot = 0; ot < 2; ot++)
#pragma unroll
            for (int reg = 0; reg < 4; reg++) {
                int p = p0 + pt * 16 + quad * 4 + reg;
                O[(size_t)p * CH + o0 + ot * 16 + m] = (acc[pt][ot][reg] + bb[ot]) * scale;
            }

    // ---- v GEMM: pt split by wave half (wv>>2), prepped wv_hi weights
    const unsigned short* Wv_g = wbuf + 65536;
    int ptv = wv >> 2;
    float bbv[2];
#pragma unroll
    for (int ot = 0; ot < 2; ot++) bbv[ot] = bv[o0 + ot * 16 + m];
    floatx4 accv[2];
    accv[0] = (floatx4){0.f, 0.f, 0.f, 0.f};
    accv[1] = (floatx4){0.f, 0.f, 0.f, 0.f};
#pragma unroll
    for (int kc = 0; kc < 4; kc++) {
        int lidx = (ptv * 16 + m) * 136 + kc * 32 + quad * 8;
        short8 av = *(const short8*)&pl[4][lidx];
#pragma unroll
        for (int ot = 0; ot < 2; ot++) {
            size_t widx = (size_t)(o0 + ot * 16 + m) * CH + kc * 32 + quad * 8;
            short8 bhv = *(const short8*)(Wv_g + widx);
            accv[ot] = __builtin_amdgcn_mfma_f32_16x16x32_bf16(av, bhv, accv[ot], 0, 0, 0);
        }
    }
    unsigned short* vhh = vh + (size_t)(wv & 3) * QTOT * 32;
#pragma unroll
    for (int ot = 0; ot < 2; ot++)
#pragma unroll
        for (int reg = 0; reg < 4; reg++) {
            int p = p0 + ptv * 16 + quad * 4 + reg;
            vhh[(size_t)p * 32 + ot * 16 + m] = f2bf(accv[ot][reg] + bbv[ot]);
        }
}

// ------ attention v10: dists via per-block MFMA GEMM ---------------------------------
// Old: each of 16 waves re-read its own 64 candidate pixels from LDS (1024
// pixel-reads vs 184 unique = 5.6x redundancy; 8 ds_read_b128/wave at the b128
// 2-way floor = ~23us of LDS serialization chip-wide). New: dists[16q x 184cand]
// computed as 12 MFMA tiles (waves 0-11, bf16 hi/lo bf16x3 -- same scheme as the
// q/k GEMM), K staged ONCE as bf16 hi/lo (same LDS bytes as old fp32 kp), dists
// to an LDS table (stride 196 kills store conflicts). Select/compact/gather are
// byte-identical to r11 (same lane<->candidate map, two-level ballot, tie-break,
// slot order). Numerics: dist error ~2^-24 rel, same class as the existing
// bf16x3 pipeline.
__global__ __launch_bounds__(1024) void attn_kernel(
    const float* __restrict__ q,    // qkf[0] [p][128] fp32
    const float* __restrict__ k,    // qkf[1]
    const unsigned short* __restrict__ vh,   // [4][QTOT][32] bf16
    unsigned short* __restrict__ att)        // [p][128] bf16
{
    __shared__ unsigned short kph[192 * 36];  // 13.5 KB  K hi (192 rows: 184 + 8 pad)
    __shared__ unsigned short kpl[192 * 36];  // 13.5 KB  K lo
    __shared__ unsigned short qsh[16 * 40];   // 1.25 KB  Q hi
    __shared__ unsigned short qsl[16 * 40];   // 1.25 KB  Q lo
    __shared__ float distT[16 * 196];         // 12.25 KB dists [query][cand]
    __shared__ uint2 slot[16][KTOP];          // 2 KB
    int h = blockIdx.y;
    int n = blockIdx.x;
    int seg = (n & 7) * 144 + (n >> 3);       // XCD-band swizzle
    int qj0 = (seg % (WW / SEG)) * SEG;
    int qi = (seg / (WW / SEG)) % HH;
    int tt = seg / ((WW / SEG) * HH);
    int t = threadIdx.x;

    // stage reflected k patch as bf16 hi/lo (rows >=184 clone row 183; their
    // dists are computed but never read)
#pragma unroll
    for (int r = 0; r < 2; r++) {
        int f = r * 1024 + t;
        if (f < 192 * 8) {
            int pix = f >> 3, d4 = f & 7;
            int spix = pix < PR * PC ? pix : PR * PC - 1;
            int ci = spix / PC, cj = spix - ci * PC;
            int gi = refl(qi + ci - 4, HH);
            int gj = refl(qj0 + cj - 4, WW);
            int gp = tt * HWS + gi * WW + gj;
            float4 kv = *(const float4*)(k + (size_t)gp * CH + h * HD + d4 * 4);
            unsigned short h0 = f2bf(kv.x), h1 = f2bf(kv.y), h2 = f2bf(kv.z), h3 = f2bf(kv.w);
            uint2 ph;
            ph.x = h0 | ((unsigned)h1 << 16); ph.y = h2 | ((unsigned)h3 << 16);
            *(uint2*)&kph[pix * 36 + d4 * 4] = ph;
            uint2 plo;
            plo.x = f2bf(kv.x - bf2f(h0)) | ((unsigned)f2bf(kv.y - bf2f(h1)) << 16);
            plo.y = f2bf(kv.z - bf2f(h2)) | ((unsigned)f2bf(kv.w - bf2f(h3)) << 16);
            *(uint2*)&kpl[pix * 36 + d4 * 4] = plo;
        }
    }
    // stage q: 16 queries x 32 ch
    if (t < 512) {
        int qq = t >> 5, ch = t & 31;
        int p = tt * HWS + qi * WW + qj0 + qq;
        float qv = q[(size_t)p * CH + h * HD + ch];
        unsigned short qhi = f2bf(qv);
        qsh[qq * 40 + ch] = qhi;
        qsl[qq * 40 + ch] = f2bf(qv - bf2f(qhi));
    }
    int wv = t >> 6, lane = t & 63;
    int wvu = __builtin_amdgcn_readfirstlane(wv);
    if (lane < KTOP) slot[wvu][lane] = make_uint2(0u, 0u);
    __syncthreads();

    int m = lane & 15, quad = lane >> 4;
    // ---- MFMA dist tiles: wave w computes dists for cands [16w,16w+16)
    if (wvu < 12) {
        short8 ah = *(const short8*)&qsh[m * 40 + quad * 8];
        short8 al = *(const short8*)&qsl[m * 40 + quad * 8];
        int krow = wvu * 16 + m;
        short8 bh = *(const short8*)&kph[krow * 36 + quad * 8];
        short8 bl = *(const short8*)&kpl[krow * 36 + quad * 8];
        floatx4 dacc = (floatx4){0.f, 0.f, 0.f, 0.f};
        dacc = __builtin_amdgcn_mfma_f32_16x16x32_bf16(ah, bh, dacc, 0, 0, 0);
        dacc = __builtin_amdgcn_mfma_f32_16x16x32_bf16(ah, bl, dacc, 0, 0, 0);
        dacc = __builtin_amdgcn_mfma_f32_16x16x32_bf16(al, bh, dacc, 0, 0, 0);
        // D[query=quad*4+reg][cand=16*wvu+m] (C layout: row=(lane>>4)*4+reg, col=lane&15)
#pragma unroll
        for (int reg = 0; reg < 4; reg++)
            distT[(quad * 4 + reg) * 196 + wvu * 16 + m] = dacc[reg];
    }
    __syncthreads();

    int ci = lane >> 3, cjo = lane & 7;
    int di = ci - 4, dj = cjo - 4;
    int rowoff = tt * HWS + refl(qi + di, HH) * WW;
    const unsigned long long below = (1ull << lane) - 1ull;
    const unsigned short* vhh = vh + (size_t)h * QTOT * 32;

    int ql = wvu;                    // this wave's query within the segment
    int qj = qj0 + ql;
    int p = tt * HWS + qi * WW + qj;
    int pixq = ci * PC + ql + cjo;
    float dist = distT[wvu * 196 + pixq];

    // ---- order-preserving key; exp hoisted out of the select dependency
    unsigned u = __float_as_uint(dist);
    unsigned key = (u & 0x80000000u) ? ~u : (u | 0x80000000u);
    unsigned khi = key >> 16, klo = key & 0xffffu;
    // softmax without shift: dists are O(1e-3), exp is exact-safe
    float e = __expf(dist);

    // ---- level 1: 16-ballot threshold search on the high 16 bits.
    unsigned Lh = 0u;
#pragma unroll
    for (int bit = 15; bit >= 0; --bit) {
        unsigned C = Lh | (1u << bit);
        unsigned long long b = __ballot(khi >= C);
        Lh = (__popcll(b) >= KTOP) ? C : Lh;
    }
    bool gth = khi > Lh;
    bool eqh = (khi == Lh);
    unsigned long long gtmh = __ballot(gth);
    unsigned long long eqmh = __ballot(eqh);
    int need = KTOP - __popcll(gtmh);          // >= 1; class size >= need
    bool selb;
    unsigned long long selm;
    if (__popcll(eqmh) == need) {
        // fast path (wave-uniform): class exactly fills -> all of it selected.
        selb = gth || eqh;
        selm = gtmh | eqmh;
    } else {
        // refine: need-th largest klo within the hi-eq class
        unsigned Ll = 0u;
#pragma unroll
        for (int bit = 15; bit >= 0; --bit) {
            unsigned C = Ll | (1u << bit);
            unsigned long long b = __ballot(klo >= C) & eqmh;
            Ll = (__popcll(b) >= need) ? C : Ll;
        }
        unsigned long long gtml = __ballot(klo > Ll) & eqmh;
        unsigned long long eqml = __ballot(klo == Ll) & eqmh;
        int needl = need - __popcll(gtml);     // >= 1
        int rk = __popcll(eqml & below);
        bool gtl = eqh && (klo > Ll);
        bool eql = eqh && (klo == Ll);
        selb = gth || gtl || (eql && rk < needl);
        selm = __ballot(selb);
    }
    int rksel = __builtin_amdgcn_mbcnt_hi(
        (unsigned)(selm >> 32), __builtin_amdgcn_mbcnt_lo((unsigned)selm, 0));
    int cpix = rowoff + refl(qj + dj, WW);
    if (selb && rksel < KTOP)
        slot[wvu][rksel] = make_uint2(__float_as_uint(e), (unsigned)(cpix << 5));

    // ---- weighted v gather, halves split across lanes (0-31: slots 0-7,
    // 32-63: slots 8-15), combined with one xor-32 shuffle per sum
    const int d = lane & (HD - 1);
    const int half8 = (lane >> 5) * 8;
    float acc = 0.f, denom = 0.f;
#pragma unroll
    for (int r = 0; r < 8; r++) {
        uint2 sp = slot[wvu][half8 + r];
        float a0 = __uint_as_float(sp.x);
        denom += a0;
        acc += a0 * bf2f(vhh[(size_t)sp.y + d]);
    }
    acc += __shfl_xor(acc, 32);
    denom += __shfl_xor(denom, 32);
    if (lane < HD)
        att[(size_t)p * CH + h * HD + lane] =
            f2bf(acc * __builtin_amdgcn_rcpf(denom));
}

// ------ proj via bf16 MFMA: prepped pj_hi weights direct from L2 --------------------
__global__ __launch_bounds__(256) void proj_mfma(
    const unsigned short* __restrict__ A,   // att_bf [p][c] bf16
    const unsigned short* __restrict__ wbuf,
    const float* __restrict__ bias,
    float* __restrict__ out)                // NCHW fp32
{
    const unsigned short* Wg = wbuf + 81920;
    int t = threadIdx.x;
    int wv = t >> 6, lane = t & 63;
    int m = lane & 15, quad = lane >> 4;
    int p0 = blockIdx.x * 64;
    int o0 = wv * 32;
    float bb[2][4];
#pragma unroll
    for (int ot = 0; ot < 2; ot++)
#pragma unroll
        for (int reg = 0; reg < 4; reg++) bb[ot][reg] = bias[o0 + ot * 16 + quad * 4 + reg];
    floatx4 acc[2][4];
#pragma unroll
    for (int i = 0; i < 2; i++)
#pragma unroll
        for (int jj2 = 0; jj2 < 4; jj2++) acc[i][jj2] = (floatx4){0.f, 0.f, 0.f, 0.f};
#pragma unroll
    for (int kc = 0; kc < 4; kc++) {
        short8 a[2], b[4];
#pragma unroll
        for (int ot = 0; ot < 2; ot++)
            a[ot] = *(const short8*)(Wg + (size_t)(o0 + ot * 16 + m) * CH + kc * 32 + quad * 8);
#pragma unroll
        for (int pt = 0; pt < 4; pt++)
            b[pt] = *(const short8*)(A + (size_t)(p0 + pt * 16 + m) * CH + kc * 32 + quad * 8);
#pragma unroll
        for (int ot = 0; ot < 2; ot++)
#pragma unroll
            for (int pt = 0; pt < 4; pt++)
                acc[ot][pt] = __builtin_amdgcn_mfma_f32_16x16x32_bf16(a[ot], b[pt], acc[ot][pt], 0, 0, 0);
    }
    int tt = p0 / HWS;
    int hwb = p0 - tt * HWS;
#pragma unroll
    for (int ot = 0; ot < 2; ot++)
#pragma unroll
        for (int pt = 0; pt < 4; pt++)
#pragma unroll
            for (int reg = 0; reg < 4; reg++) {
                int o = o0 + ot * 16 + quad * 4 + reg;
                int hw = hwb + pt * 16 + m;
                out[((size_t)(tt * CH + o)) * HWS + hw] = acc[ot][pt][reg] + bb[ot][reg];
            }
}

extern "C" void kernel_launch(void* const* d_in, const int* in_sizes, int n_in,
                              void* d_out, int out_size, void* d_ws, size_t ws_size,
                              hipStream_t stream) {
    const float* vid    = (const float*)d_in[0];
    const float* wq_dw  = (const float*)d_in[1];
    const float* wq_pw  = (const float*)d_in[2];
    const float* bq     = (const float*)d_in[3];
    const float* wk_dw  = (const float*)d_in[4];
    const float* wk_pw  = (const float*)d_in[5];
    const float* bk     = (const float*)d_in[6];
    const float* wv_dw  = (const float*)d_in[7];
    const float* wv_pw  = (const float*)d_in[8];
    const float* bv     = (const float*)d_in[9];
    const float* proj_w = (const float*)d_in[10];
    const float* proj_b = (const float*)d_in[11];
    float* out = (float*)d_out;

    // workspace (~28.5 MB): qkf 2*QC fp32 | vh QC bf16 | att_bf QC bf16 | wbuf
    float* qkf = (float*)d_ws;
    unsigned short* vh = (unsigned short*)(qkf + (size_t)2 * QC);
    unsigned short* att_bf = vh + (size_t)QC;
    unsigned short* wbuf = att_bf + (size_t)QC;

    wprep_kernel<<<4, 256, 0, stream>>>(wq_pw, wk_pw, wv_pw, proj_w, wbuf);
    dwqkv_kernel<<<QTOT / FPX, 512, 0, stream>>>(
        vid, wq_dw, wk_dw, wv_dw, wbuf, bq, bk, bv, qkf, vh);
    attn_kernel<<<dim3(TT * HH * (WW / SEG), 4), 1024, 0, stream>>>(
        qkf, qkf + (size_t)QC, vh, att_bf);
    proj_mfma<<<QTOT / 64, 256, 0, stream>>>(att_bf, wbuf, proj_b, out);
}

// Round 14
// 168.508 us; speedup vs baseline: 1.0180x; 1.0180x over previous
//
#include <hip/hip_runtime.h>
#include <math.h>

#define TT 2
#define CH 128
#define HH 96
#define WW 96
#define HWS 9216            // H*W
#define QTOT 18432          // T*H*W
#define QC (QTOT*CH)
#define HD 32
#define KTOP 16
#define SCALE 0.17677669529663687f  // 32^-0.5

#define SEG 16              // queries per attn block (one row segment)
#define PR 8                // patch rows
#define PC 23               // patch cols
#define PSTRIDE 36          // floats per patch pixel in LDS (144 B)

#define FPX 32              // pixels per fused dw+qkv block

// wbuf (bf16 shorts): wq_hi@0 wq_lo@16384 wk_hi@32768 wk_lo@49152 wv_hi@65536 pj_hi@81920
#define WB_TOT 98304

typedef __attribute__((ext_vector_type(8))) short short8;
typedef __attribute__((ext_vector_type(4))) float floatx4;

__device__ __forceinline__ unsigned short f2bf(float f) {
    union { float f; unsigned u; } x; x.f = f;
    unsigned r = x.u + 0x7fffu + ((x.u >> 16) & 1u);
    return (unsigned short)(r >> 16);
}
__device__ __forceinline__ float bf2f(unsigned short h) {
    return __uint_as_float(((unsigned)h) << 16);
}

__device__ __forceinline__ int refl(int x, int n) {
    x = x < 0 ? -x : x;
    return x >= n ? 2 * (n - 1) - x : x;
}

// ------ one-shot pointwise/proj weight conversion (4 blocks; runs BEFORE dwqkv) -----
__global__ __launch_bounds__(256) void wprep_kernel(
    const float* __restrict__ wq_pw, const float* __restrict__ wk_pw,
    const float* __restrict__ wv_pw, const float* __restrict__ proj_w,
    unsigned short* __restrict__ wbuf)
{
    int t = threadIdx.x;
    int y = blockIdx.x;               // 0=wq_pw(hi+lo) 1=wk_pw(hi+lo) 2=wv_pw 3=proj_w
    const float* src = y == 0 ? wq_pw : (y == 1 ? wk_pw : (y == 2 ? wv_pw : proj_w));
    unsigned short* hi = wbuf + (y == 0 ? 0 : (y == 1 ? 32768 : (y == 2 ? 65536 : 81920)));
#pragma unroll
    for (int r = 0; r < 16; r++) {
        int idx = r * 256 + t;        // float4 index, 4096 total = 128x128
        float4 w4 = *(const float4*)(src + idx * 4);
        unsigned short hx = f2bf(w4.x), hy = f2bf(w4.y), hz = f2bf(w4.z), hw = f2bf(w4.w);
        uint2 pk;
        pk.x = hx | ((unsigned)hy << 16); pk.y = hz | ((unsigned)hw << 16);
        *(uint2*)(hi + idx * 4) = pk;
        if (y < 2) {
            unsigned short lx = f2bf(w4.x - bf2f(hx)), ly = f2bf(w4.y - bf2f(hy));
            unsigned short lz = f2bf(w4.z - bf2f(hz)), lw = f2bf(w4.w - bf2f(hw));
            pk.x = lx | ((unsigned)ly << 16); pk.y = lz | ((unsigned)lw << 16);
            *(uint2*)(hi + 16384 + idx * 4) = pk;
        }
    }
}

// ------ FUSED depthwise 3x3 + bf16 split + qkv GEMMs (no intermediate HBM trip) -----
__global__ __launch_bounds__(512) void dwqkv_kernel(
    const float* __restrict__ x,
    const float* __restrict__ wqd, const float* __restrict__ wkd, const float* __restrict__ wvd,
    const unsigned short* __restrict__ wbuf,
    const float* __restrict__ bq, const float* __restrict__ bk, const float* __restrict__ bv,
    float* __restrict__ qkf,            // q -> qkf[0], k -> qkf[1] ([p][c] fp32)
    unsigned short* __restrict__ vh)    // [4][QTOT][32] bf16
{
    __shared__ float wS[3456];                    // 13.8 KB: wq|wk|wv dw taps (128x9 each)
    __shared__ unsigned short pl[5][FPX * 136];   // 43.5 KB: q_hi,q_lo,k_hi,k_lo,v
    int t = threadIdx.x;
    for (int r = t; r < 1152; r += 512) {
        wS[r] = wqd[r]; wS[1152 + r] = wkd[r]; wS[2304 + r] = wvd[r];
    }
    int p0 = blockIdx.x * FPX;
    int tt0 = p0 / HWS;
    int hw0 = p0 - tt0 * HWS;
    int i0 = hw0 / WW, j0 = hw0 - i0 * WW;        // block-uniform (32 | 96)
    int px = t & 31, cgp = t >> 5;                // cgp in [0,16)
    int c0 = cgp * 8;
    int j = j0 + px;

    int off[9]; float mk[9];
#pragma unroll
    for (int r = 0; r < 3; r++) {
        int ii = i0 + r - 1;
        float rm = (ii >= 0 && ii < HH) ? 1.f : 0.f;
        int iic = ii < 0 ? 0 : (ii >= HH ? HH - 1 : ii);
#pragma unroll
        for (int s = 0; s < 3; s++) {
            int jj = j + s - 1;
            float cm = (jj >= 0 && jj < WW) ? 1.f : 0.f;
            int jjc = jj < 0 ? 0 : (jj >= WW ? WW - 1 : jj);
            off[r * 3 + s] = iic * WW + jjc;
            mk[r * 3 + s] = rm * cm;
        }
    }
    __syncthreads();   // weights staged

    unsigned qh[4], ql2[4], kh[4], kl[4], vh4[4];
#pragma unroll
    for (int ic = 0; ic < 8; ic += 2) {
        float sv[3][2];
#pragma unroll
        for (int u = 0; u < 2; u++) {
            int c = c0 + ic + u;
            const float* xp = x + (size_t)(tt0 * CH + c) * HWS;
            const float* w0 = &wS[c * 9];
            const float* w1 = &wS[1152 + c * 9];
            const float* w2 = &wS[2304 + c * 9];
            float s0 = 0.f, s1 = 0.f, s2 = 0.f;
#pragma unroll
            for (int q9 = 0; q9 < 9; q9++) {
                float xv = xp[off[q9]] * mk[q9];   // mask=1 -> exact; mask=0 -> +0.0
                s0 += xv * w0[q9]; s1 += xv * w1[q9]; s2 += xv * w2[q9];
            }
            sv[0][u] = s0; sv[1][u] = s1; sv[2][u] = s2;
        }
        int w = ic >> 1;
        unsigned short h0 = f2bf(sv[0][0]), h1 = f2bf(sv[0][1]);
        qh[w] = h0 | ((unsigned)h1 << 16);
        ql2[w] = f2bf(sv[0][0] - bf2f(h0)) | ((unsigned)f2bf(sv[0][1] - bf2f(h1)) << 16);
        h0 = f2bf(sv[1][0]); h1 = f2bf(sv[1][1]);
        kh[w] = h0 | ((unsigned)h1 << 16);
        kl[w] = f2bf(sv[1][0] - bf2f(h0)) | ((unsigned)f2bf(sv[1][1] - bf2f(h1)) << 16);
        vh4[w] = f2bf(sv[2][0]) | ((unsigned)f2bf(sv[2][1]) << 16);
    }
    int lb = px * 136 + c0;
    uint4 pk;
    pk.x = qh[0];  pk.y = qh[1];  pk.z = qh[2];  pk.w = qh[3];  *(uint4*)&pl[0][lb] = pk;
    pk.x = ql2[0]; pk.y = ql2[1]; pk.z = ql2[2]; pk.w = ql2[3]; *(uint4*)&pl[1][lb] = pk;
    pk.x = kh[0];  pk.y = kh[1];  pk.z = kh[2];  pk.w = kh[3];  *(uint4*)&pl[2][lb] = pk;
    pk.x = kl[0];  pk.y = kl[1];  pk.z = kl[2];  pk.w = kl[3];  *(uint4*)&pl[3][lb] = pk;
    pk.x = vh4[0]; pk.y = vh4[1]; pk.z = vh4[2]; pk.w = vh4[3]; *(uint4*)&pl[4][lb] = pk;
    __syncthreads();

    // ---- phase 2: GEMMs. waves 0-3: q, waves 4-7: k (o0 = (wv&3)*32)
    int wv = t >> 6, lane = t & 63;
    int m = lane & 15, quad = lane >> 4;
    int o0 = (wv & 3) * 32;
    bool isQ = wv < 4;
    const unsigned short* Wh_g = wbuf + (isQ ? 0 : 32768);
    const unsigned short* Wl_g = Wh_g + 16384;
    const unsigned short* Ah = pl[isQ ? 0 : 2];
    const unsigned short* Al = pl[isQ ? 1 : 3];
    const float* bias = isQ ? bq : bk;
    float scale = isQ ? SCALE : 1.f;
    float* O = qkf + (isQ ? 0 : (size_t)QC);
    float bb[2];
#pragma unroll
    for (int ot = 0; ot < 2; ot++) bb[ot] = bias[o0 + ot * 16 + m];
    floatx4 acc[2][2];
#pragma unroll
    for (int i = 0; i < 2; i++)
#pragma unroll
        for (int jj2 = 0; jj2 < 2; jj2++) acc[i][jj2] = (floatx4){0.f, 0.f, 0.f, 0.f};
#pragma unroll
    for (int kc = 0; kc < 4; kc++) {
        short8 avh[2], avl[2], bh2[2], bl2[2];
#pragma unroll
        for (int pt = 0; pt < 2; pt++) {
            int lidx = (pt * 16 + m) * 136 + kc * 32 + quad * 8;
            avh[pt] = *(const short8*)&Ah[lidx];
            avl[pt] = *(const short8*)&Al[lidx];
        }
#pragma unroll
        for (int ot = 0; ot < 2; ot++) {
            size_t widx = (size_t)(o0 + ot * 16 + m) * CH + kc * 32 + quad * 8;
            bh2[ot] = *(const short8*)(Wh_g + widx);
            bl2[ot] = *(const short8*)(Wl_g + widx);
        }
#pragma unroll
        for (int pt = 0; pt < 2; pt++)
#pragma unroll
            for (int ot = 0; ot < 2; ot++) {
                acc[pt][ot] = __builtin_amdgcn_mfma_f32_16x16x32_bf16(avh[pt], bh2[ot], acc[pt][ot], 0, 0, 0);
                acc[pt][ot] = __builtin_amdgcn_mfma_f32_16x16x32_bf16(avh[pt], bl2[ot], acc[pt][ot], 0, 0, 0);
                acc[pt][ot] = __builtin_amdgcn_mfma_f32_16x16x32_bf16(avl[pt], bh2[ot], acc[pt][ot], 0, 0, 0);
            }
    }
#pragma unroll
    for (int pt = 0; pt < 2; pt++)
#pragma unroll
        for (int ot = 0; ot < 2; ot++)
#pragma unroll
            for (int reg = 0; reg < 4; reg++) {
                int p = p0 + pt * 16 + quad * 4 + reg;
                O[(size_t)p * CH + o0 + ot * 16 + m] = (acc[pt][ot][reg] + bb[ot]) * scale;
            }

    // ---- v GEMM: pt split by wave half (wv>>2), prepped wv_hi weights
    const unsigned short* Wv_g = wbuf + 65536;
    int ptv = wv >> 2;
    float bbv[2];
#pragma unroll
    for (int ot = 0; ot < 2; ot++) bbv[ot] = bv[o0 + ot * 16 + m];
    floatx4 accv[2];
    accv[0] = (floatx4){0.f, 0.f, 0.f, 0.f};
    accv[1] = (floatx4){0.f, 0.f, 0.f, 0.f};
#pragma unroll
    for (int kc = 0; kc < 4; kc++) {
        int lidx = (ptv * 16 + m) * 136 + kc * 32 + quad * 8;
        short8 av = *(const short8*)&pl[4][lidx];
#pragma unroll
        for (int ot = 0; ot < 2; ot++) {
            size_t widx = (size_t)(o0 + ot * 16 + m) * CH + kc * 32 + quad * 8;
            short8 bhv = *(const short8*)(Wv_g + widx);
            accv[ot] = __builtin_amdgcn_mfma_f32_16x16x32_bf16(av, bhv, accv[ot], 0, 0, 0);
        }
    }
    unsigned short* vhh = vh + (size_t)(wv & 3) * QTOT * 32;
#pragma unroll
    for (int ot = 0; ot < 2; ot++)
#pragma unroll
        for (int reg = 0; reg < 4; reg++) {
            int p = p0 + ptv * 16 + quad * 4 + reg;
            vhh[(size_t)p * 32 + ot * 16 + m] = f2bf(accv[ot][reg] + bbv[ot]);
        }
}

// ------ attention (r11 best-known: fp32 kp staging + two-level ballot select) -------
__global__ __launch_bounds__(1024) void attn_kernel(
    const float* __restrict__ q,    // qkf[0] [p][128] fp32
    const float* __restrict__ k,    // qkf[1]
    const unsigned short* __restrict__ vh,   // [4][QTOT][32] bf16
    unsigned short* __restrict__ att)        // [p][128] bf16
{
    __shared__ float kp[PR * PC * PSTRIDE];   // 25.9 KB
    __shared__ uint2 slot[16][KTOP];          // per-wave compaction, 2 KB
    int h = blockIdx.y;
    int n = blockIdx.x;
    int seg = (n & 7) * 144 + (n >> 3);       // XCD-band swizzle
    int qj0 = (seg % (WW / SEG)) * SEG;
    int qi = (seg / (WW / SEG)) % HH;
    int tt = seg / ((WW / SEG) * HH);
    int t = threadIdx.x;

#pragma unroll
    for (int r = 0; r < 2; r++) {
        int f = r * 1024 + t;
        if (f < PR * PC * 8) {
            int pix = f >> 3, d4 = f & 7;
            int ci = pix / PC, cj = pix - ci * PC;
            int gi = refl(qi + ci - 4, HH);
            int gj = refl(qj0 + cj - 4, WW);
            int gp = tt * HWS + gi * WW + gj;
            *(float4*)(&kp[pix * PSTRIDE + d4 * 4]) =
                *(const float4*)(k + (size_t)gp * CH + h * HD + d4 * 4);
        }
    }

    int wv = t >> 6, lane = t & 63;
    int wvu = __builtin_amdgcn_readfirstlane(wv);
    if (lane < KTOP) slot[wvu][lane] = make_uint2(0u, 0u);
    __syncthreads();

    int ci = lane >> 3, cjo = lane & 7;
    int di = ci - 4, dj = cjo - 4;
    int rowoff = tt * HWS + refl(qi + di, HH) * WW;
    const unsigned long long below = (1ull << lane) - 1ull;
    const unsigned short* vhh = vh + (size_t)h * QTOT * 32;

    int ql = wvu;
    int qj = qj0 + ql;
    int p = tt * HWS + qi * WW + qj;

    const float* qp = q + (size_t)p * CH + h * HD;
    int pixq = ci * PC + ql + cjo;
    const float* kr = &kp[pixq * PSTRIDE];
    float dist = 0.f;
#pragma unroll
    for (int dd = 0; dd < 8; dd++) {
        float4 qv = *(const float4*)(qp + dd * 4);
        float4 kv = *(const float4*)(kr + dd * 4);
        dist += qv.x * kv.x + qv.y * kv.y + qv.z * kv.z + qv.w * kv.w;
    }

    unsigned u = __float_as_uint(dist);
    unsigned key = (u & 0x80000000u) ? ~u : (u | 0x80000000u);
    unsigned khi = key >> 16, klo = key & 0xffffu;
    float e = __expf(dist);

    unsigned Lh = 0u;
#pragma unroll
    for (int bit = 15; bit >= 0; --bit) {
        unsigned C = Lh | (1u << bit);
        unsigned long long b = __ballot(khi >= C);
        Lh = (__popcll(b) >= KTOP) ? C : Lh;
    }
    bool gth = khi > Lh;
    bool eqh = (khi == Lh);
    unsigned long long gtmh = __ballot(gth);
    unsigned long long eqmh = __ballot(eqh);
    int need = KTOP - __popcll(gtmh);
    bool selb;
    unsigned long long selm;
    if (__popcll(eqmh) == need) {
        selb = gth || eqh;
        selm = gtmh | eqmh;
    } else {
        unsigned Ll = 0u;
#pragma unroll
        for (int bit = 15; bit >= 0; --bit) {
            unsigned C = Ll | (1u << bit);
            unsigned long long b = __ballot(klo >= C) & eqmh;
            Ll = (__popcll(b) >= need) ? C : Ll;
        }
        unsigned long long gtml = __ballot(klo > Ll) & eqmh;
        unsigned long long eqml = __ballot(klo == Ll) & eqmh;
        int needl = need - __popcll(gtml);
        int rk = __popcll(eqml & below);
        bool gtl = eqh && (klo > Ll);
        bool eql = eqh && (klo == Ll);
        selb = gth || gtl || (eql && rk < needl);
        selm = __ballot(selb);
    }
    int rksel = __builtin_amdgcn_mbcnt_hi(
        (unsigned)(selm >> 32), __builtin_amdgcn_mbcnt_lo((unsigned)selm, 0));
    int cpix = rowoff + refl(qj + dj, WW);
    if (selb && rksel < KTOP)
        slot[wvu][rksel] = make_uint2(__float_as_uint(e), (unsigned)(cpix << 5));

    const int d = lane & (HD - 1);
    const int half8 = (lane >> 5) * 8;
    float acc = 0.f, denom = 0.f;
#pragma unroll
    for (int r = 0; r < 8; r++) {
        uint2 sp = slot[wvu][half8 + r];
        float a0 = __uint_as_float(sp.x);
        denom += a0;
        acc += a0 * bf2f(vhh[(size_t)sp.y + d]);
    }
    acc += __shfl_xor(acc, 32);
    denom += __shfl_xor(denom, 32);
    if (lane < HD)
        att[(size_t)p * CH + h * HD + lane] =
            f2bf(acc * __builtin_amdgcn_rcpf(denom));
}

// ------ proj via bf16 MFMA: prepped pj_hi weights direct from L2 --------------------
__global__ __launch_bounds__(256) void proj_mfma(
    const unsigned short* __restrict__ A,   // att_bf [p][c] bf16
    const unsigned short* __restrict__ wbuf,
    const float* __restrict__ bias,
    float* __restrict__ out)                // NCHW fp32
{
    const unsigned short* Wg = wbuf + 81920;
    int t = threadIdx.x;
    int wv = t >> 6, lane = t & 63;
    int m = lane & 15, quad = lane >> 4;
    int p0 = blockIdx.x * 64;
    int o0 = wv * 32;
    float bb[2][4];
#pragma unroll
    for (int ot = 0; ot < 2; ot++)
#pragma unroll
        for (int reg = 0; reg < 4; reg++) bb[ot][reg] = bias[o0 + ot * 16 + quad * 4 + reg];
    floatx4 acc[2][4];
#pragma unroll
    for (int i = 0; i < 2; i++)
#pragma unroll
        for (int jj2 = 0; jj2 < 4; jj2++) acc[i][jj2] = (floatx4){0.f, 0.f, 0.f, 0.f};
#pragma unroll
    for (int kc = 0; kc < 4; kc++) {
        short8 a[2], b[4];
#pragma unroll
        for (int ot = 0; ot < 2; ot++)
            a[ot] = *(const short8*)(Wg + (size_t)(o0 + ot * 16 + m) * CH + kc * 32 + quad * 8);
#pragma unroll
        for (int pt = 0; pt < 4; pt++)
            b[pt] = *(const short8*)(A + (size_t)(p0 + pt * 16 + m) * CH + kc * 32 + quad * 8);
#pragma unroll
        for (int ot = 0; ot < 2; ot++)
#pragma unroll
            for (int pt = 0; pt < 4; pt++)
                acc[ot][pt] = __builtin_amdgcn_mfma_f32_16x16x32_bf16(a[ot], b[pt], acc[ot][pt], 0, 0, 0);
    }
    int tt = p0 / HWS;
    int hwb = p0 - tt * HWS;
#pragma unroll
    for (int ot = 0; ot < 2; ot++)
#pragma unroll
        for (int pt = 0; pt < 4; pt++)
#pragma unroll
            for (int reg = 0; reg < 4; reg++) {
                int o = o0 + ot * 16 + quad * 4 + reg;
                int hw = hwb + pt * 16 + m;
                out[((size_t)(tt * CH + o)) * HWS + hw] = acc[ot][pt][reg] + bb[ot][reg];
            }
}

extern "C" void kernel_launch(void* const* d_in, const int* in_sizes, int n_in,
                              void* d_out, int out_size, void* d_ws, size_t ws_size,
                              hipStream_t stream) {
    const float* vid    = (const float*)d_in[0];
    const float* wq_dw  = (const float*)d_in[1];
    const float* wq_pw  = (const float*)d_in[2];
    const float* bq     = (const float*)d_in[3];
    const float* wk_dw  = (const float*)d_in[4];
    const float* wk_pw  = (const float*)d_in[5];
    const float* bk     = (const float*)d_in[6];
    const float* wv_dw  = (const float*)d_in[7];
    const float* wv_pw  = (const float*)d_in[8];
    const float* bv     = (const float*)d_in[9];
    const float* proj_w = (const float*)d_in[10];
    const float* proj_b = (const float*)d_in[11];
    float* out = (float*)d_out;

    // workspace (~28.5 MB): qkf 2*QC fp32 | vh QC bf16 | att_bf QC bf16 | wbuf
    float* qkf = (float*)d_ws;
    unsigned short* vh = (unsigned short*)(qkf + (size_t)2 * QC);
    unsigned short* att_bf = vh + (size_t)QC;
    unsigned short* wbuf = att_bf + (size_t)QC;

    wprep_kernel<<<4, 256, 0, stream>>>(wq_pw, wk_pw, wv_pw, proj_w, wbuf);
    dwqkv_kernel<<<QTOT / FPX, 512, 0, stream>>>(
        vid, wq_dw, wk_dw, wv_dw, wbuf, bq, bk, bv, qkf, vh);
    attn_kernel<<<dim3(TT * HH * (WW / SEG), 4), 1024, 0, stream>>>(
        qkf, qkf + (size_t)QC, vh, att_bf);
    proj_mfma<<<QTOT / 64, 256, 0, stream>>>(att_bf, wbuf, proj_b, out);
}